// Round 13
// baseline (106.030 us; speedup 1.0000x reference)
//
#include <hip/hip_runtime.h>
#include <hip/hip_fp16.h>
#include <math.h>

// Problem: E=8, B=4096, D=128, N=8192.
// out[b,n] = softmax_n( x[b,:] @ W[e(b)] + bias[e(b)] ) for the (unique) bin e(b), else 0.
//
// Round 13 = exact R10 structure (98.2 us best: separate bin(1024thr)/convert/gemm/softmax)
// with ONE change: gemm row-tile 128 -> 256 (1024 threads, 16 waves in 4x4 split).
// Rationale (traffic arithmetic): gemm is L2-B-reread-bound: 40 row-tiles x 16.8 MB
// B-reads ~ 670 MB @ 34.5 TB/s ~ 19.5 us. 256-row tiles -> <=24 row-tiles -> ~390 MB.
// Each wave keeps R10's exact shape (64 rows x 32 cols, acc[4][2]) -> same per-thread
// VGPR, same K-loop body, bit-identical numerics.
// R12 lesson: convert+bin fusion REVERTED (cost +7 us; 256-thr bin block gated it).
// Lessons kept: no min-waves launch_bounds (R3/R6); no per-lane gathered K-loop
// streams (R4); single-bf16 within threshold (R9); fp16 logit staging (R10);
// one change per round (R11/R12).

#define B_ROWS 4096
#define D_DIM  128
#define N_DIM  8192
#define E_NUM  8

typedef __attribute__((ext_vector_type(8))) __bf16 bf16x8;
typedef __attribute__((ext_vector_type(4))) float  f32x4;

__device__ __forceinline__ unsigned short f2bf(float f) {
    unsigned int u = __float_as_uint(f);
    unsigned int r = u + 0x7FFFu + ((u >> 16) & 1u);   // round-to-nearest-even
    return (unsigned short)(r >> 16);
}

// ws int layout:
//   [0]         n_tiles
//   [8..79]     tile_e
//   [96..167]   tile_start
//   [184..255]  tile_cnt
//   [448..455]  per-expert counts
//   [512..4607] sorted row indices (grouped by expert)
// byte 65536+ : W bf16 [e][n][k]  (16 MB)

__global__ __launch_bounds__(1024)
void bin_kernel(const float* __restrict__ x,
                const float* __restrict__ tlo,
                const float* __restrict__ thi,
                int* __restrict__ ws_i, int m_tile) {
    __shared__ int cnt_s[E_NUM];
    __shared__ int off_s[E_NUM];
    __shared__ int cur_s[E_NUM];
    __shared__ int e_row[B_ROWS];

    int tid = threadIdx.x;
    if (tid < E_NUM) cnt_s[tid] = 0;
    __syncthreads();

    for (int r = tid; r < B_ROWS; r += 1024) {
        float th = x[(size_t)r * D_DIM];   // x[r, 0]
        int e = -1;
        #pragma unroll
        for (int i = 0; i < E_NUM; ++i) {
            if (e < 0 && th > tlo[i] && th <= thi[i]) e = i;  // first match
        }
        e_row[r] = e;
        if (e >= 0) atomicAdd(&cnt_s[e], 1);
    }
    __syncthreads();

    if (tid == 0) {
        int off = 0;
        for (int e = 0; e < E_NUM; ++e) {
            ws_i[448 + e] = cnt_s[e];
            off_s[e] = off;
            cur_s[e] = off;
            off += cnt_s[e];
        }
        int nt = 0;
        for (int e = 0; e < E_NUM; ++e) {
            int c = cnt_s[e];
            int s = off_s[e];
            for (int t0 = 0; t0 < c && nt < 72; t0 += m_tile) {
                ws_i[8 + nt]   = e;
                ws_i[96 + nt]  = s + t0;
                ws_i[184 + nt] = (c - t0 < m_tile) ? (c - t0) : m_tile;
                ++nt;
            }
        }
        ws_i[0] = nt;
    }
    __syncthreads();

    for (int r = tid; r < B_ROWS; r += 1024) {
        int e = e_row[r];
        if (e >= 0) {
            int p = atomicAdd(&cur_s[e], 1);
            ws_i[512 + p] = r;
        }
    }
}

// Convert active experts' W to bf16, TRANSPOSED to [e][n][k] (k contiguous).
// LDS transpose with pad 136 + chunk-XOR swizzle.
__global__ __launch_bounds__(256)
void convert_kernel(const float* __restrict__ W,
                    const int* __restrict__ ws_i,
                    unsigned short* __restrict__ wh) {
    int bid = blockIdx.x;
    int t = threadIdx.x;
    int e = bid >> 7;                       // 8 experts x 128 n-chunks of 64
    if (ws_i[448 + e] == 0) return;         // expert inactive -> skip
    int n0 = (bid & 127) * 64;
    __shared__ __align__(16) unsigned short hi_s[64 * 136];
    const float* Wp = W + (size_t)e * D_DIM * N_DIM + n0;
    #pragma unroll
    for (int i = 0; i < 8; ++i) {
        int idx = i * 256 + t;              // 2048 float4 = 128 d-rows x 16
        int d  = idx >> 4;
        int j4 = idx & 15;
        float4 v = *(const float4*)(Wp + (size_t)d * N_DIM + j4 * 4);
        float fv[4] = {v.x, v.y, v.z, v.w};
        #pragma unroll
        for (int c = 0; c < 4; ++c) {
            int row = j4 * 4 + c;
            int dsw = d ^ (((row >> 2) & 7) << 3);   // chunk-XOR swizzle
            hi_s[row * 136 + dsw] = f2bf(fv[c]);
        }
    }
    __syncthreads();
    unsigned short* whp = wh + ((size_t)e * N_DIM + n0) * D_DIM;
    #pragma unroll
    for (int i = 0; i < 4; ++i) {
        int idx = i * 256 + t;              // 1024 16B-chunks = 64 n-rows x 16
        int nl = idx >> 4;
        int ck = idx & 15;
        int cks = ck ^ ((nl >> 2) & 7);     // inverse of the write swizzle
        *(uint4*)(whp + (size_t)nl * D_DIM + ck * 8) = *(const uint4*)(&hi_s[nl * 136 + cks * 8]);
    }
}

// MFMA GEMM v13: block = 256 rows x 128 cols, 1024 threads = 16 waves in 4x4
// (row x col) split; wave = 64 rows x 32 cols (EXACT R10 wave shape, acc[4][2]).
// Single bf16 A plane in 64 KB XOR-swizzled LDS. K=128 in 4 steps, all 4 B-pairs
// prefetched upfront. Epilogue: direct fp16 stores (barrier-free wave drain).
__global__ __launch_bounds__(1024)
void gemm_mfma(const float* __restrict__ x,
               const unsigned short* __restrict__ wh,
               const float* __restrict__ bias, const int* __restrict__ ws_i,
               float* __restrict__ out) {
    int bt = blockIdx.y;
    if (bt >= ws_i[0]) return;
    int e   = ws_i[8 + bt];
    int seg = ws_i[96 + bt];
    int cnt = ws_i[184 + bt];
    const int* sorted = ws_i + 512;

    __shared__ __align__(16) unsigned short a_s[256 * 128];  // 64 KB bf16 A tile

    int tid = threadIdx.x;
    // stage gathered x rows, fp32 -> bf16 on the fly, XOR-swizzled: byte ^= (row&7)<<4
    #pragma unroll
    for (int i = 0; i < 4; ++i) {
        int idx = i * 1024 + tid;    // 4096 chunks = 256 rows x 16 x 16B(bf16)
        int row = idx >> 4;
        int ck  = idx & 15;
        unsigned short hq[8] = {0, 0, 0, 0, 0, 0, 0, 0};
        if (row < cnt) {
            int r = sorted[seg + row];
            const float* xp = x + (size_t)r * D_DIM + ck * 8;
            float4 va = *(const float4*)(xp);
            float4 vb = *(const float4*)(xp + 4);
            hq[0] = f2bf(va.x); hq[1] = f2bf(va.y); hq[2] = f2bf(va.z); hq[3] = f2bf(va.w);
            hq[4] = f2bf(vb.x); hq[5] = f2bf(vb.y); hq[6] = f2bf(vb.z); hq[7] = f2bf(vb.w);
        }
        int boff = row * 256 + ((ck * 16) ^ ((row & 7) << 4));
        *(uint4*)((char*)a_s + boff) = *(const uint4*)hq;
    }
    __syncthreads();   // only barrier: K-loop + epilogue are barrier-free

    int lane = tid & 63;
    int wave = tid >> 6;            // 16 waves: wm = wave>>2 (64-row group), wn = wave&3
    int wm = wave >> 2, wn = wave & 3;
    int l15 = lane & 15, q = lane >> 4;
    int colbase = blockIdx.x * 128 + wn * 32;

    const unsigned short* whp = wh + (size_t)e * N_DIM * D_DIM;

    f32x4 acc[4][2];
    #pragma unroll
    for (int mi = 0; mi < 4; ++mi) {
        acc[mi][0] = (f32x4){0.f, 0.f, 0.f, 0.f};
        acc[mi][1] = (f32x4){0.f, 0.f, 0.f, 0.f};
    }

    // B base for this lane: col = colbase + {0,16} + l15, k offset q*8
    const unsigned short* base0 = whp + (size_t)(colbase + l15) * D_DIM + q * 8;

    // prefetch ALL 4 K-steps' B fragment pairs upfront (8 x 16B loads in flight)
    bf16x8 b0[4], b1[4];
    #pragma unroll
    for (int s = 0; s < 4; ++s) {
        b0[s] = *(const bf16x8*)(base0 + s * 32);
        b1[s] = *(const bf16x8*)(base0 + s * 32 + 16 * D_DIM);
    }

    #pragma unroll
    for (int s = 0; s < 4; ++s) {
        const int kb = (s * 32 + q * 8) * 2;   // byte offset in K
        #pragma unroll
        for (int mi = 0; mi < 4; ++mi) {
            int row  = wm * 64 + mi * 16 + l15;
            int aoff = row * 256 + (kb ^ ((row & 7) << 4));
            bf16x8 a = *(const bf16x8*)((const char*)a_s + aoff);
            acc[mi][0] = __builtin_amdgcn_mfma_f32_16x16x32_bf16(a, b0[s], acc[mi][0], 0, 0, 0);
            acc[mi][1] = __builtin_amdgcn_mfma_f32_16x16x32_bf16(a, b1[s], acc[mi][1], 0, 0, 0);
        }
    }

    // epilogue (R10): C/D layout col=lane&15, row=(lane>>4)*4+reg.
    // Direct fp16 stores into the first N_DIM halfs of the row's fp32 slot.
    const float* bp = bias + (size_t)e * N_DIM;
    float bv0 = bp[colbase + l15];
    float bv1 = bp[colbase + 16 + l15];

    #pragma unroll
    for (int mi = 0; mi < 4; ++mi) {
        #pragma unroll
        for (int reg = 0; reg < 4; ++reg) {
            int m = wm * 64 + mi * 16 + q * 4 + reg;
            if (m < cnt) {
                int r = sorted[seg + m];
                __half* lp = (__half*)(out + (size_t)r * N_DIM);
                lp[colbase + l15]      = __float2half(acc[mi][0][reg] + bv0);
                lp[colbase + 16 + l15] = __float2half(acc[mi][1][reg] + bv1);
            }
        }
    }
}

// Softmax over fp16 logits staged in the first 16KB of each 32KB fp32 row slot.
__global__ __launch_bounds__(256)
void softmax_f16(const float* __restrict__ x,
                 const float* __restrict__ tlo,
                 const float* __restrict__ thi,
                 float* __restrict__ out) {
    int r = blockIdx.x;
    int tid = threadIdx.x;
    float th = x[(size_t)r * D_DIM];
    bool valid = false;
    #pragma unroll
    for (int i = 0; i < E_NUM; ++i) {
        if (th > tlo[i] && th <= thi[i]) valid = true;
    }
    float* row = out + (size_t)r * N_DIM;

    if (!valid) {
        float4 z = make_float4(0.f, 0.f, 0.f, 0.f);
        #pragma unroll
        for (int c = 0; c < 4; ++c) {
            *(float4*)(row + c * 2048 + tid * 8)     = z;
            *(float4*)(row + c * 2048 + tid * 8 + 4) = z;
        }
        return;
    }

    float vv[32];
    float mx = -INFINITY;
    const __half* hp = (const __half*)row;
    #pragma unroll
    for (int c = 0; c < 4; ++c) {
        uint4 u = *(const uint4*)(hp + c * 2048 + tid * 8);
        const __half2* h2 = (const __half2*)&u;
        #pragma unroll
        for (int j = 0; j < 4; ++j) {
            float2 f = __half22float2(h2[j]);
            vv[c * 8 + 2 * j]     = f.x;
            vv[c * 8 + 2 * j + 1] = f.y;
            mx = fmaxf(mx, fmaxf(f.x, f.y));
        }
    }

    __shared__ float red[8];
    #pragma unroll
    for (int o = 1; o < 64; o <<= 1) mx = fmaxf(mx, __shfl_xor(mx, o));
    if ((tid & 63) == 0) red[tid >> 6] = mx;
    __syncthreads();
    mx = fmaxf(fmaxf(red[0], red[1]), fmaxf(red[2], red[3]));

    float sum = 0.f;
    #pragma unroll
    for (int i = 0; i < 32; ++i) {
        vv[i] = expf(vv[i] - mx);
        sum += vv[i];
    }
    #pragma unroll
    for (int o = 1; o < 64; o <<= 1) sum += __shfl_xor(sum, o);
    if ((tid & 63) == 0) red[4 + (tid >> 6)] = sum;
    __syncthreads();
    sum = red[4] + red[5] + red[6] + red[7];

    float inv = 1.0f / sum;
    #pragma unroll
    for (int c = 0; c < 4; ++c) {
        float4 o0, o1;
        o0.x = vv[c * 8 + 0] * inv; o0.y = vv[c * 8 + 1] * inv;
        o0.z = vv[c * 8 + 2] * inv; o0.w = vv[c * 8 + 3] * inv;
        o1.x = vv[c * 8 + 4] * inv; o1.y = vv[c * 8 + 5] * inv;
        o1.z = vv[c * 8 + 6] * inv; o1.w = vv[c * 8 + 7] * inv;
        *(float4*)(row + c * 2048 + tid * 8)     = o0;
        *(float4*)(row + c * 2048 + tid * 8 + 4) = o1;
    }
}

// ---------------- fallback path (workspace too small): bin + fp32 GEMM + softmax ------

__device__ __forceinline__ void fma4(float4& ac, float xs, const float4& wv) {
    ac.x = fmaf(xs, wv.x, ac.x);
    ac.y = fmaf(xs, wv.y, ac.y);
    ac.z = fmaf(xs, wv.z, ac.z);
    ac.w = fmaf(xs, wv.w, ac.w);
}

__global__ __launch_bounds__(256)
void gemm_kernel(const float* __restrict__ x,
                 const float* __restrict__ W,
                 const float* __restrict__ bias,
                 const int* __restrict__ ws_i,
                 float* __restrict__ out) {
    int bt = blockIdx.y;
    if (bt >= ws_i[0]) return;
    int e   = ws_i[8 + bt];
    int seg = ws_i[96 + bt];
    int cnt = ws_i[184 + bt];
    const int* sorted = ws_i + 512;

    __shared__ float x_s[64][D_DIM];
    __shared__ int   rows_s[64];

    int tid = threadIdx.x;
    if (tid < 64) rows_s[tid] = (tid < cnt) ? sorted[seg + tid] : -1;
    __syncthreads();

    #pragma unroll
    for (int c = 0; c < 8; ++c) {
        int idx = c * 256 + tid;
        int i = idx >> 5;
        int k4 = idx & 31;
        int r = rows_s[i];
        float4 v;
        if (r >= 0) v = *(const float4*)(x + (size_t)r * D_DIM + k4 * 4);
        else        v = make_float4(0.f, 0.f, 0.f, 0.f);
        *(float4*)(&x_s[i][k4 * 4]) = v;
    }
    __syncthreads();

    int nidx = tid & 63;
    int mg   = tid >> 6;
    int col  = blockIdx.x * 256 + nidx * 4;
    const float* Wp = W + ((size_t)e * D_DIM) * N_DIM + col;

    float4 acc[16];
    #pragma unroll
    for (int i = 0; i < 16; ++i) acc[i] = make_float4(0.f, 0.f, 0.f, 0.f);

    for (int k = 0; k < D_DIM; k += 4) {
        float4 w0 = *(const float4*)(Wp + (size_t)(k + 0) * N_DIM);
        float4 w1 = *(const float4*)(Wp + (size_t)(k + 1) * N_DIM);
        float4 w2 = *(const float4*)(Wp + (size_t)(k + 2) * N_DIM);
        float4 w3 = *(const float4*)(Wp + (size_t)(k + 3) * N_DIM);
        #pragma unroll
        for (int i = 0; i < 16; ++i) {
            float4 xv = *(const float4*)(&x_s[mg * 16 + i][k]);
            fma4(acc[i], xv.x, w0);
            fma4(acc[i], xv.y, w1);
            fma4(acc[i], xv.z, w2);
            fma4(acc[i], xv.w, w3);
        }
    }

    float4 bv = *(const float4*)(bias + (size_t)e * N_DIM + col);
    #pragma unroll
    for (int i = 0; i < 16; ++i) {
        int m = mg * 16 + i;
        if (m < cnt) {
            int r = rows_s[m];
            float4 o = acc[i];
            o.x += bv.x; o.y += bv.y; o.z += bv.z; o.w += bv.w;
            *(float4*)(out + (size_t)r * N_DIM + col) = o;
        }
    }
}

__global__ __launch_bounds__(256)
void softmax_kernel(const float* __restrict__ x,
                    const float* __restrict__ tlo,
                    const float* __restrict__ thi,
                    float* __restrict__ out) {
    int r = blockIdx.x;
    int tid = threadIdx.x;
    float th = x[(size_t)r * D_DIM];
    bool valid = false;
    #pragma unroll
    for (int i = 0; i < E_NUM; ++i) {
        if (th > tlo[i] && th <= thi[i]) valid = true;
    }
    float* row = out + (size_t)r * N_DIM;

    if (!valid) {
        float4 z = make_float4(0.f, 0.f, 0.f, 0.f);
        #pragma unroll
        for (int c = 0; c < 8; ++c)
            *(float4*)(row + c * 1024 + tid * 4) = z;
        return;
    }

    float4 v[8];
    float mx = -INFINITY;
    #pragma unroll
    for (int c = 0; c < 8; ++c) {
        v[c] = *(const float4*)(row + c * 1024 + tid * 4);
        mx = fmaxf(mx, fmaxf(fmaxf(v[c].x, v[c].y), fmaxf(v[c].z, v[c].w)));
    }

    __shared__ float red[8];
    #pragma unroll
    for (int o = 1; o < 64; o <<= 1) mx = fmaxf(mx, __shfl_xor(mx, o));
    if ((tid & 63) == 0) red[tid >> 6] = mx;
    __syncthreads();
    mx = fmaxf(fmaxf(red[0], red[1]), fmaxf(red[2], red[3]));

    float sum = 0.f;
    #pragma unroll
    for (int c = 0; c < 8; ++c) {
        v[c].x = expf(v[c].x - mx);
        v[c].y = expf(v[c].y - mx);
        v[c].z = expf(v[c].z - mx);
        v[c].w = expf(v[c].w - mx);
        sum += v[c].x + v[c].y + v[c].z + v[c].w;
    }
    #pragma unroll
    for (int o = 1; o < 64; o <<= 1) sum += __shfl_xor(sum, o);
    if ((tid & 63) == 0) red[4 + (tid >> 6)] = sum;
    __syncthreads();
    sum = red[4] + red[5] + red[6] + red[7];

    float inv = 1.0f / sum;
    #pragma unroll
    for (int c = 0; c < 8; ++c) {
        float4 o;
        o.x = v[c].x * inv; o.y = v[c].y * inv;
        o.z = v[c].z * inv; o.w = v[c].w * inv;
        *(float4*)(row + c * 1024 + tid * 4) = o;
    }
}

extern "C" void kernel_launch(void* const* d_in, const int* in_sizes, int n_in,
                              void* d_out, int out_size, void* d_ws, size_t ws_size,
                              hipStream_t stream) {
    const float* x   = (const float*)d_in[0];
    const float* W   = (const float*)d_in[1];
    const float* b   = (const float*)d_in[2];
    const float* tlo = (const float*)d_in[3];
    const float* thi = (const float*)d_in[4];
    float* out = (float*)d_out;
    int* ws_i = (int*)d_ws;

    const size_t meta = 65536;
    const size_t wsz = (size_t)E_NUM * N_DIM * D_DIM;
    unsigned short* wh = (unsigned short*)((char*)d_ws + meta);
    size_t need = meta + wsz * sizeof(unsigned short);
    bool fast = (ws_size >= need);

    if (fast) {
        bin_kernel<<<1, 1024, 0, stream>>>(x, tlo, thi, ws_i, 256);
        convert_kernel<<<1024, 256, 0, stream>>>(W, ws_i, wh);
        // tiles with m_tile=256: <= 16 full + 8 partials = 24
        gemm_mfma<<<dim3(N_DIM / 128, 24), 1024, 0, stream>>>(x, wh, b, ws_i, out);
        softmax_f16<<<B_ROWS, 256, 0, stream>>>(x, tlo, thi, out);
    } else {
        bin_kernel<<<1, 1024, 0, stream>>>(x, tlo, thi, ws_i, 64);
        gemm_kernel<<<dim3(N_DIM / 256, 72), 256, 0, stream>>>(x, W, b, ws_i, out);
        softmax_kernel<<<B_ROWS, 256, 0, stream>>>(x, tlo, thi, out);
    }
}

// Round 14
// 98.327 us; speedup vs baseline: 1.0783x; 1.0783x over previous
//
#include <hip/hip_runtime.h>
#include <hip/hip_fp16.h>
#include <math.h>

// Problem: E=8, B=4096, D=128, N=8192.
// out[b,n] = softmax_n( x[b,:] @ W[e(b)] + bias[e(b)] ) for the (unique) bin e(b), else 0.
//
// Round 14 = CONTROL: exact R10 resubmission (byte-identical kernels, best measured
// 98.2 us). R11/R12/R13 each changed one thing on top of this and ALL landed at
// 105.5-106.4 -- same value as R9 which moves 134 MB more traffic. That cluster
// suggests a ~105 us plateau + R10's 98.2 possibly being run variance; the three
// "regression attributions" were cross-probe without a base re-run (rigor rule).
// This round re-measures the base config unchanged: reproduces ~98 -> real, keep;
// lands ~105 -> noise established, R10 structure still best-known.
// Pipeline: bin (1 block, 1024 thr) -> convert W->bf16 [e][n][k] -> MFMA gemm
// (128x128 tile, 512 thr, 2x4 waves, fp16 logit staging in-place) -> softmax_f16.

#define B_ROWS 4096
#define D_DIM  128
#define N_DIM  8192
#define E_NUM  8

typedef __attribute__((ext_vector_type(8))) __bf16 bf16x8;
typedef __attribute__((ext_vector_type(4))) float  f32x4;

__device__ __forceinline__ unsigned short f2bf(float f) {
    unsigned int u = __float_as_uint(f);
    unsigned int r = u + 0x7FFFu + ((u >> 16) & 1u);   // round-to-nearest-even
    return (unsigned short)(r >> 16);
}

// ws int layout:
//   [0]         n_tiles
//   [8..79]     tile_e
//   [96..167]   tile_start
//   [184..255]  tile_cnt
//   [448..455]  per-expert counts
//   [512..4607] sorted row indices (grouped by expert)
// byte 65536+ : W bf16 [e][n][k]  (16 MB)

__global__ __launch_bounds__(1024)
void bin_kernel(const float* __restrict__ x,
                const float* __restrict__ tlo,
                const float* __restrict__ thi,
                int* __restrict__ ws_i, int m_tile) {
    __shared__ int cnt_s[E_NUM];
    __shared__ int off_s[E_NUM];
    __shared__ int cur_s[E_NUM];
    __shared__ int e_row[B_ROWS];

    int tid = threadIdx.x;
    if (tid < E_NUM) cnt_s[tid] = 0;
    __syncthreads();

    for (int r = tid; r < B_ROWS; r += 1024) {
        float th = x[(size_t)r * D_DIM];   // x[r, 0]
        int e = -1;
        #pragma unroll
        for (int i = 0; i < E_NUM; ++i) {
            if (e < 0 && th > tlo[i] && th <= thi[i]) e = i;  // first match
        }
        e_row[r] = e;
        if (e >= 0) atomicAdd(&cnt_s[e], 1);
    }
    __syncthreads();

    if (tid == 0) {
        int off = 0;
        for (int e = 0; e < E_NUM; ++e) {
            ws_i[448 + e] = cnt_s[e];
            off_s[e] = off;
            cur_s[e] = off;
            off += cnt_s[e];
        }
        int nt = 0;
        for (int e = 0; e < E_NUM; ++e) {
            int c = cnt_s[e];
            int s = off_s[e];
            for (int t0 = 0; t0 < c && nt < 72; t0 += m_tile) {
                ws_i[8 + nt]   = e;
                ws_i[96 + nt]  = s + t0;
                ws_i[184 + nt] = (c - t0 < m_tile) ? (c - t0) : m_tile;
                ++nt;
            }
        }
        ws_i[0] = nt;
    }
    __syncthreads();

    for (int r = tid; r < B_ROWS; r += 1024) {
        int e = e_row[r];
        if (e >= 0) {
            int p = atomicAdd(&cur_s[e], 1);
            ws_i[512 + p] = r;
        }
    }
}

// Convert active experts' W to bf16, TRANSPOSED to [e][n][k] (k contiguous) so MFMA
// B-fragments are 16B contiguous loads. LDS transpose with pad 136 + chunk-XOR swizzle.
__global__ __launch_bounds__(256)
void convert_kernel(const float* __restrict__ W,
                    const int* __restrict__ ws_i,
                    unsigned short* __restrict__ wh) {
    int bid = blockIdx.x;
    int t = threadIdx.x;
    int e = bid >> 7;                       // 8 experts x 128 n-chunks of 64
    if (ws_i[448 + e] == 0) return;         // expert inactive -> skip
    int n0 = (bid & 127) * 64;
    __shared__ __align__(16) unsigned short hi_s[64 * 136];
    const float* Wp = W + (size_t)e * D_DIM * N_DIM + n0;
    #pragma unroll
    for (int i = 0; i < 8; ++i) {
        int idx = i * 256 + t;              // 2048 float4 = 128 d-rows x 16
        int d  = idx >> 4;
        int j4 = idx & 15;
        float4 v = *(const float4*)(Wp + (size_t)d * N_DIM + j4 * 4);
        float fv[4] = {v.x, v.y, v.z, v.w};
        #pragma unroll
        for (int c = 0; c < 4; ++c) {
            int row = j4 * 4 + c;
            int dsw = d ^ (((row >> 2) & 7) << 3);   // chunk-XOR swizzle
            hi_s[row * 136 + dsw] = f2bf(fv[c]);
        }
    }
    __syncthreads();
    unsigned short* whp = wh + ((size_t)e * N_DIM + n0) * D_DIM;
    #pragma unroll
    for (int i = 0; i < 4; ++i) {
        int idx = i * 256 + t;              // 1024 16B-chunks = 64 n-rows x 16
        int nl = idx >> 4;
        int ck = idx & 15;
        int cks = ck ^ ((nl >> 2) & 7);     // inverse of the write swizzle
        *(uint4*)(whp + (size_t)nl * D_DIM + ck * 8) = *(const uint4*)(&hi_s[nl * 136 + cks * 8]);
    }
}

// MFMA GEMM (R10 exact): block = 128 rows x 128 cols, 512 threads = 8 waves in 2x4
// split; wave = 64 rows x 32 cols, acc[4][2] = 32 VGPR. Single bf16 A plane in 32 KB
// XOR-swizzled LDS (x converted fp32->bf16 during staging). K=128 in 4 steps; all 4
// B fragment pairs prefetched upfront. Epilogue: direct fp16 stores into the first
// 16KB of each out-row's 32KB fp32 slot (barrier-free wave drain).
__global__ __launch_bounds__(512)
void gemm_mfma(const float* __restrict__ x,
               const unsigned short* __restrict__ wh,
               const float* __restrict__ bias, const int* __restrict__ ws_i,
               float* __restrict__ out) {
    int bt = blockIdx.y;
    if (bt >= ws_i[0]) return;
    int e   = ws_i[8 + bt];
    int seg = ws_i[96 + bt];
    int cnt = ws_i[184 + bt];
    const int* sorted = ws_i + 512;

    __shared__ __align__(16) unsigned short a_s[128 * 128];  // 32 KB bf16 A tile

    int tid = threadIdx.x;
    // stage gathered x rows, fp32 -> bf16 on the fly, XOR-swizzled: byte ^= (row&7)<<4
    #pragma unroll
    for (int i = 0; i < 4; ++i) {
        int idx = i * 512 + tid;     // 2048 chunks = 128 rows x 16 x 16B(bf16)
        int row = idx >> 4;
        int ck  = idx & 15;
        unsigned short hq[8] = {0, 0, 0, 0, 0, 0, 0, 0};
        if (row < cnt) {
            int r = sorted[seg + row];
            const float* xp = x + (size_t)r * D_DIM + ck * 8;
            float4 va = *(const float4*)(xp);
            float4 vb = *(const float4*)(xp + 4);
            hq[0] = f2bf(va.x); hq[1] = f2bf(va.y); hq[2] = f2bf(va.z); hq[3] = f2bf(va.w);
            hq[4] = f2bf(vb.x); hq[5] = f2bf(vb.y); hq[6] = f2bf(vb.z); hq[7] = f2bf(vb.w);
        }
        int boff = row * 256 + ((ck * 16) ^ ((row & 7) << 4));
        *(uint4*)((char*)a_s + boff) = *(const uint4*)hq;
    }
    __syncthreads();   // only barrier: K-loop + epilogue are barrier-free

    int lane = tid & 63;
    int wave = tid >> 6;            // wm = wave>>2 (64-row half), wn = wave&3 (32 cols)
    int wm = wave >> 2, wn = wave & 3;
    int l15 = lane & 15, q = lane >> 4;
    int colbase = blockIdx.x * 128 + wn * 32;

    const unsigned short* whp = wh + (size_t)e * N_DIM * D_DIM;

    f32x4 acc[4][2];
    #pragma unroll
    for (int mi = 0; mi < 4; ++mi) {
        acc[mi][0] = (f32x4){0.f, 0.f, 0.f, 0.f};
        acc[mi][1] = (f32x4){0.f, 0.f, 0.f, 0.f};
    }

    // B base for this lane: col = colbase + {0,16} + l15, k offset q*8
    const unsigned short* base0 = whp + (size_t)(colbase + l15) * D_DIM + q * 8;

    // prefetch ALL 4 K-steps' B fragment pairs upfront (8 x 16B loads in flight)
    bf16x8 b0[4], b1[4];
    #pragma unroll
    for (int s = 0; s < 4; ++s) {
        b0[s] = *(const bf16x8*)(base0 + s * 32);
        b1[s] = *(const bf16x8*)(base0 + s * 32 + 16 * D_DIM);
    }

    #pragma unroll
    for (int s = 0; s < 4; ++s) {
        const int kb = (s * 32 + q * 8) * 2;   // byte offset in K
        #pragma unroll
        for (int mi = 0; mi < 4; ++mi) {
            int row  = wm * 64 + mi * 16 + l15;
            int aoff = row * 256 + (kb ^ ((row & 7) << 4));
            bf16x8 a = *(const bf16x8*)((const char*)a_s + aoff);
            acc[mi][0] = __builtin_amdgcn_mfma_f32_16x16x32_bf16(a, b0[s], acc[mi][0], 0, 0, 0);
            acc[mi][1] = __builtin_amdgcn_mfma_f32_16x16x32_bf16(a, b1[s], acc[mi][1], 0, 0, 0);
        }
    }

    // epilogue: C/D layout col=lane&15, row=(lane>>4)*4+reg.
    // Direct fp16 stores into the first N_DIM halfs of the row's fp32 slot.
    const float* bp = bias + (size_t)e * N_DIM;
    float bv0 = bp[colbase + l15];
    float bv1 = bp[colbase + 16 + l15];

    #pragma unroll
    for (int mi = 0; mi < 4; ++mi) {
        #pragma unroll
        for (int reg = 0; reg < 4; ++reg) {
            int m = wm * 64 + mi * 16 + q * 4 + reg;
            if (m < cnt) {
                int r = sorted[seg + m];
                __half* lp = (__half*)(out + (size_t)r * N_DIM);
                lp[colbase + l15]      = __float2half(acc[mi][0][reg] + bv0);
                lp[colbase + 16 + l15] = __float2half(acc[mi][1][reg] + bv1);
            }
        }
    }
}

// Softmax over fp16 logits staged in the first 16KB of each 32KB fp32 row slot.
// Reads all 32 values into registers BEFORE the reduction barriers, then overwrites
// the row with fp32 probabilities.
__global__ __launch_bounds__(256)
void softmax_f16(const float* __restrict__ x,
                 const float* __restrict__ tlo,
                 const float* __restrict__ thi,
                 float* __restrict__ out) {
    int r = blockIdx.x;
    int tid = threadIdx.x;
    float th = x[(size_t)r * D_DIM];
    bool valid = false;
    #pragma unroll
    for (int i = 0; i < E_NUM; ++i) {
        if (th > tlo[i] && th <= thi[i]) valid = true;
    }
    float* row = out + (size_t)r * N_DIM;

    if (!valid) {
        float4 z = make_float4(0.f, 0.f, 0.f, 0.f);
        #pragma unroll
        for (int c = 0; c < 4; ++c) {
            *(float4*)(row + c * 2048 + tid * 8)     = z;
            *(float4*)(row + c * 2048 + tid * 8 + 4) = z;
        }
        return;
    }

    float vv[32];
    float mx = -INFINITY;
    const __half* hp = (const __half*)row;
    #pragma unroll
    for (int c = 0; c < 4; ++c) {
        uint4 u = *(const uint4*)(hp + c * 2048 + tid * 8);
        const __half2* h2 = (const __half2*)&u;
        #pragma unroll
        for (int j = 0; j < 4; ++j) {
            float2 f = __half22float2(h2[j]);
            vv[c * 8 + 2 * j]     = f.x;
            vv[c * 8 + 2 * j + 1] = f.y;
            mx = fmaxf(mx, fmaxf(f.x, f.y));
        }
    }

    __shared__ float red[8];
    #pragma unroll
    for (int o = 1; o < 64; o <<= 1) mx = fmaxf(mx, __shfl_xor(mx, o));
    if ((tid & 63) == 0) red[tid >> 6] = mx;
    __syncthreads();
    mx = fmaxf(fmaxf(red[0], red[1]), fmaxf(red[2], red[3]));

    float sum = 0.f;
    #pragma unroll
    for (int i = 0; i < 32; ++i) {
        vv[i] = expf(vv[i] - mx);
        sum += vv[i];
    }
    #pragma unroll
    for (int o = 1; o < 64; o <<= 1) sum += __shfl_xor(sum, o);
    if ((tid & 63) == 0) red[4 + (tid >> 6)] = sum;
    __syncthreads();
    sum = red[4] + red[5] + red[6] + red[7];

    float inv = 1.0f / sum;
    #pragma unroll
    for (int c = 0; c < 4; ++c) {
        float4 o0, o1;
        o0.x = vv[c * 8 + 0] * inv; o0.y = vv[c * 8 + 1] * inv;
        o0.z = vv[c * 8 + 2] * inv; o0.w = vv[c * 8 + 3] * inv;
        o1.x = vv[c * 8 + 4] * inv; o1.y = vv[c * 8 + 5] * inv;
        o1.z = vv[c * 8 + 6] * inv; o1.w = vv[c * 8 + 7] * inv;
        *(float4*)(row + c * 2048 + tid * 8)     = o0;
        *(float4*)(row + c * 2048 + tid * 8 + 4) = o1;
    }
}

// ---------------- fallback path (workspace too small): bin + fp32 GEMM + softmax ------

__device__ __forceinline__ void fma4(float4& ac, float xs, const float4& wv) {
    ac.x = fmaf(xs, wv.x, ac.x);
    ac.y = fmaf(xs, wv.y, ac.y);
    ac.z = fmaf(xs, wv.z, ac.z);
    ac.w = fmaf(xs, wv.w, ac.w);
}

__global__ __launch_bounds__(256)
void gemm_kernel(const float* __restrict__ x,
                 const float* __restrict__ W,
                 const float* __restrict__ bias,
                 const int* __restrict__ ws_i,
                 float* __restrict__ out) {
    int bt = blockIdx.y;
    if (bt >= ws_i[0]) return;
    int e   = ws_i[8 + bt];
    int seg = ws_i[96 + bt];
    int cnt = ws_i[184 + bt];
    const int* sorted = ws_i + 512;

    __shared__ float x_s[64][D_DIM];
    __shared__ int   rows_s[64];

    int tid = threadIdx.x;
    if (tid < 64) rows_s[tid] = (tid < cnt) ? sorted[seg + tid] : -1;
    __syncthreads();

    #pragma unroll
    for (int c = 0; c < 8; ++c) {
        int idx = c * 256 + tid;
        int i = idx >> 5;
        int k4 = idx & 31;
        int r = rows_s[i];
        float4 v;
        if (r >= 0) v = *(const float4*)(x + (size_t)r * D_DIM + k4 * 4);
        else        v = make_float4(0.f, 0.f, 0.f, 0.f);
        *(float4*)(&x_s[i][k4 * 4]) = v;
    }
    __syncthreads();

    int nidx = tid & 63;
    int mg   = tid >> 6;
    int col  = blockIdx.x * 256 + nidx * 4;
    const float* Wp = W + ((size_t)e * D_DIM) * N_DIM + col;

    float4 acc[16];
    #pragma unroll
    for (int i = 0; i < 16; ++i) acc[i] = make_float4(0.f, 0.f, 0.f, 0.f);

    for (int k = 0; k < D_DIM; k += 4) {
        float4 w0 = *(const float4*)(Wp + (size_t)(k + 0) * N_DIM);
        float4 w1 = *(const float4*)(Wp + (size_t)(k + 1) * N_DIM);
        float4 w2 = *(const float4*)(Wp + (size_t)(k + 2) * N_DIM);
        float4 w3 = *(const float4*)(Wp + (size_t)(k + 3) * N_DIM);
        #pragma unroll
        for (int i = 0; i < 16; ++i) {
            float4 xv = *(const float4*)(&x_s[mg * 16 + i][k]);
            fma4(acc[i], xv.x, w0);
            fma4(acc[i], xv.y, w1);
            fma4(acc[i], xv.z, w2);
            fma4(acc[i], xv.w, w3);
        }
    }

    float4 bv = *(const float4*)(bias + (size_t)e * N_DIM + col);
    #pragma unroll
    for (int i = 0; i < 16; ++i) {
        int m = mg * 16 + i;
        if (m < cnt) {
            int r = rows_s[m];
            float4 o = acc[i];
            o.x += bv.x; o.y += bv.y; o.z += bv.z; o.w += bv.w;
            *(float4*)(out + (size_t)r * N_DIM + col) = o;
        }
    }
}

__global__ __launch_bounds__(256)
void softmax_kernel(const float* __restrict__ x,
                    const float* __restrict__ tlo,
                    const float* __restrict__ thi,
                    float* __restrict__ out) {
    int r = blockIdx.x;
    int tid = threadIdx.x;
    float th = x[(size_t)r * D_DIM];
    bool valid = false;
    #pragma unroll
    for (int i = 0; i < E_NUM; ++i) {
        if (th > tlo[i] && th <= thi[i]) valid = true;
    }
    float* row = out + (size_t)r * N_DIM;

    if (!valid) {
        float4 z = make_float4(0.f, 0.f, 0.f, 0.f);
        #pragma unroll
        for (int c = 0; c < 8; ++c)
            *(float4*)(row + c * 1024 + tid * 4) = z;
        return;
    }

    float4 v[8];
    float mx = -INFINITY;
    #pragma unroll
    for (int c = 0; c < 8; ++c) {
        v[c] = *(const float4*)(row + c * 1024 + tid * 4);
        mx = fmaxf(mx, fmaxf(fmaxf(v[c].x, v[c].y), fmaxf(v[c].z, v[c].w)));
    }

    __shared__ float red[8];
    #pragma unroll
    for (int o = 1; o < 64; o <<= 1) mx = fmaxf(mx, __shfl_xor(mx, o));
    if ((tid & 63) == 0) red[tid >> 6] = mx;
    __syncthreads();
    mx = fmaxf(fmaxf(red[0], red[1]), fmaxf(red[2], red[3]));

    float sum = 0.f;
    #pragma unroll
    for (int c = 0; c < 8; ++c) {
        v[c].x = expf(v[c].x - mx);
        v[c].y = expf(v[c].y - mx);
        v[c].z = expf(v[c].z - mx);
        v[c].w = expf(v[c].w - mx);
        sum += v[c].x + v[c].y + v[c].z + v[c].w;
    }
    #pragma unroll
    for (int o = 1; o < 64; o <<= 1) sum += __shfl_xor(sum, o);
    if ((tid & 63) == 0) red[4 + (tid >> 6)] = sum;
    __syncthreads();
    sum = red[4] + red[5] + red[6] + red[7];

    float inv = 1.0f / sum;
    #pragma unroll
    for (int c = 0; c < 8; ++c) {
        float4 o;
        o.x = v[c].x * inv; o.y = v[c].y * inv;
        o.z = v[c].z * inv; o.w = v[c].w * inv;
        *(float4*)(row + c * 1024 + tid * 4) = o;
    }
}

extern "C" void kernel_launch(void* const* d_in, const int* in_sizes, int n_in,
                              void* d_out, int out_size, void* d_ws, size_t ws_size,
                              hipStream_t stream) {
    const float* x   = (const float*)d_in[0];
    const float* W   = (const float*)d_in[1];
    const float* b   = (const float*)d_in[2];
    const float* tlo = (const float*)d_in[3];
    const float* thi = (const float*)d_in[4];
    float* out = (float*)d_out;
    int* ws_i = (int*)d_ws;

    const size_t meta = 65536;
    const size_t wsz = (size_t)E_NUM * N_DIM * D_DIM;
    unsigned short* wh = (unsigned short*)((char*)d_ws + meta);
    size_t need = meta + wsz * sizeof(unsigned short);
    bool fast = (ws_size >= need);

    bin_kernel<<<1, 1024, 0, stream>>>(x, tlo, thi, ws_i, fast ? 128 : 64);
    if (fast) {
        convert_kernel<<<1024, 256, 0, stream>>>(W, ws_i, wh);
        // tiles <= 32 full + 8 partials = 40
        gemm_mfma<<<dim3(N_DIM / 128, 40), 512, 0, stream>>>(x, wh, b, ws_i, out);
        softmax_f16<<<B_ROWS, 256, 0, stream>>>(x, tlo, thi, out);
    } else {
        gemm_kernel<<<dim3(N_DIM / 256, 72), 256, 0, stream>>>(x, W, b, ws_i, out);
        softmax_kernel<<<B_ROWS, 256, 0, stream>>>(x, tlo, thi, out);
    }
}

// Round 15
// 94.388 us; speedup vs baseline: 1.1233x; 1.0417x over previous
//
#include <hip/hip_runtime.h>
#include <hip/hip_fp16.h>
#include <math.h>

// Problem: E=8, B=4096, D=128, N=8192.
// out[b,n] = softmax_n( x[b,:] @ W[e(b)] + bias[e(b)] ) for the (unique) bin e(b), else 0.
//
// Round 15 = R14 (twice-verified 98.2/98.3 us base) + ONE change: bin+convert fused
// with bin as BLOCK 0 at 1024 threads (R12's failed fusion had bin LAST at 256 thr --
// both suspects fixed). Convert blocks 1..1024 are unconditional (no ws_i read), so
// bin's ~5 us serial slot overlaps convert's 1024 blocks. gemm/softmax byte-identical.
// Expected: bin+convert 15 -> ~10 us. If ~105 instead: fusion is inherently costly,
// revert to R14.
// Lessons kept: no min-waves launch_bounds (R3/R6); no per-lane gathered K-loop
// streams (R4); single-bf16 within threshold (R9); fp16 logit staging (R10);
// one change per round + control re-runs for attribution (R11-R14).

#define B_ROWS 4096
#define D_DIM  128
#define N_DIM  8192
#define E_NUM  8

typedef __attribute__((ext_vector_type(8))) __bf16 bf16x8;
typedef __attribute__((ext_vector_type(4))) float  f32x4;

__device__ __forceinline__ unsigned short f2bf(float f) {
    unsigned int u = __float_as_uint(f);
    unsigned int r = u + 0x7FFFu + ((u >> 16) & 1u);   // round-to-nearest-even
    return (unsigned short)(r >> 16);
}

// ws int layout:
//   [0]         n_tiles
//   [8..79]     tile_e
//   [96..167]   tile_start
//   [184..255]  tile_cnt
//   [448..455]  per-expert counts
//   [512..4607] sorted row indices (grouped by expert)
// byte 65536+ : W bf16 [e][n][k]  (16 MB)

// ---------------- fused bin (block 0, 1024 thr) + convert (blocks 1..1024) ----------
__global__ __launch_bounds__(1024)
void bin_convert_kernel(const float* __restrict__ x, const float* __restrict__ W,
                        const float* __restrict__ tlo, const float* __restrict__ thi,
                        int* __restrict__ ws_i, unsigned short* __restrict__ wh) {
    __shared__ __align__(16) unsigned short shbuf[64 * 136];   // 17408 B, dual-use
    int bid = blockIdx.x;
    int t = threadIdx.x;

    if (bid == 0) {
        // ---- bin: exact R14 bin_kernel body, 1024 threads, m_tile=128 ----
        int* e_row = (int*)shbuf;          // 4096 ints = 16384 B
        int* cnt_s = e_row + B_ROWS;       // +32 B
        int* off_s = cnt_s + E_NUM;
        int* cur_s = off_s + E_NUM;        // total 16480 B <= 17408

        if (t < E_NUM) cnt_s[t] = 0;
        __syncthreads();

        for (int r = t; r < B_ROWS; r += 1024) {
            float th = x[(size_t)r * D_DIM];   // x[r, 0]
            int e = -1;
            #pragma unroll
            for (int i = 0; i < E_NUM; ++i) {
                if (e < 0 && th > tlo[i] && th <= thi[i]) e = i;  // first match
            }
            e_row[r] = e;
            if (e >= 0) atomicAdd(&cnt_s[e], 1);
        }
        __syncthreads();

        if (t == 0) {
            int off = 0;
            for (int e = 0; e < E_NUM; ++e) {
                ws_i[448 + e] = cnt_s[e];
                off_s[e] = off;
                cur_s[e] = off;
                off += cnt_s[e];
            }
            int nt = 0;
            for (int e = 0; e < E_NUM; ++e) {
                int c = cnt_s[e];
                int s = off_s[e];
                for (int t0 = 0; t0 < c && nt < 72; t0 += 128) {
                    ws_i[8 + nt]   = e;
                    ws_i[96 + nt]  = s + t0;
                    ws_i[184 + nt] = (c - t0 < 128) ? (c - t0) : 128;
                    ++nt;
                }
            }
            ws_i[0] = nt;
        }
        __syncthreads();

        for (int r = t; r < B_ROWS; r += 1024) {
            int e = e_row[r];
            if (e >= 0) {
                int p = atomicAdd(&cur_s[e], 1);
                ws_i[512 + p] = r;
            }
        }
    } else {
        // ---- convert chunk (bid-1): unconditional, 1024 threads ----
        unsigned short* hi_s = shbuf;
        int cb = bid - 1;
        int e  = cb >> 7;                   // 8 experts x 128 n-chunks of 64
        int n0 = (cb & 127) * 64;
        const float* Wp = W + (size_t)e * D_DIM * N_DIM + n0;
        #pragma unroll
        for (int i = 0; i < 2; ++i) {
            int idx = i * 1024 + t;         // 2048 float4 = 128 d-rows x 16
            int d  = idx >> 4;
            int j4 = idx & 15;
            float4 v = *(const float4*)(Wp + (size_t)d * N_DIM + j4 * 4);
            float fv[4] = {v.x, v.y, v.z, v.w};
            #pragma unroll
            for (int c = 0; c < 4; ++c) {
                int row = j4 * 4 + c;
                int dsw = d ^ (((row >> 2) & 7) << 3);   // chunk-XOR swizzle
                hi_s[row * 136 + dsw] = f2bf(fv[c]);
            }
        }
        __syncthreads();
        unsigned short* whp = wh + ((size_t)e * N_DIM + n0) * D_DIM;
        {
            int idx = t;                    // 1024 16B-chunks = 64 n-rows x 16
            int nl = idx >> 4;
            int ck = idx & 15;
            int cks = ck ^ ((nl >> 2) & 7); // inverse of the write swizzle
            *(uint4*)(whp + (size_t)nl * D_DIM + ck * 8) = *(const uint4*)(&hi_s[nl * 136 + cks * 8]);
        }
    }
}

// MFMA GEMM (R10/R14 exact): block = 128 rows x 128 cols, 512 threads = 8 waves in 2x4
// split; wave = 64 rows x 32 cols, acc[4][2] = 32 VGPR. Single bf16 A plane in 32 KB
// XOR-swizzled LDS (x converted fp32->bf16 during staging). K=128 in 4 steps; all 4
// B fragment pairs prefetched upfront. Epilogue: direct fp16 stores into the first
// 16KB of each out-row's 32KB fp32 slot (barrier-free wave drain).
__global__ __launch_bounds__(512)
void gemm_mfma(const float* __restrict__ x,
               const unsigned short* __restrict__ wh,
               const float* __restrict__ bias, const int* __restrict__ ws_i,
               float* __restrict__ out) {
    int bt = blockIdx.y;
    if (bt >= ws_i[0]) return;
    int e   = ws_i[8 + bt];
    int seg = ws_i[96 + bt];
    int cnt = ws_i[184 + bt];
    const int* sorted = ws_i + 512;

    __shared__ __align__(16) unsigned short a_s[128 * 128];  // 32 KB bf16 A tile

    int tid = threadIdx.x;
    // stage gathered x rows, fp32 -> bf16 on the fly, XOR-swizzled: byte ^= (row&7)<<4
    #pragma unroll
    for (int i = 0; i < 4; ++i) {
        int idx = i * 512 + tid;     // 2048 chunks = 128 rows x 16 x 16B(bf16)
        int row = idx >> 4;
        int ck  = idx & 15;
        unsigned short hq[8] = {0, 0, 0, 0, 0, 0, 0, 0};
        if (row < cnt) {
            int r = sorted[seg + row];
            const float* xp = x + (size_t)r * D_DIM + ck * 8;
            float4 va = *(const float4*)(xp);
            float4 vb = *(const float4*)(xp + 4);
            hq[0] = f2bf(va.x); hq[1] = f2bf(va.y); hq[2] = f2bf(va.z); hq[3] = f2bf(va.w);
            hq[4] = f2bf(vb.x); hq[5] = f2bf(vb.y); hq[6] = f2bf(vb.z); hq[7] = f2bf(vb.w);
        }
        int boff = row * 256 + ((ck * 16) ^ ((row & 7) << 4));
        *(uint4*)((char*)a_s + boff) = *(const uint4*)hq;
    }
    __syncthreads();   // only barrier: K-loop + epilogue are barrier-free

    int lane = tid & 63;
    int wave = tid >> 6;            // wm = wave>>2 (64-row half), wn = wave&3 (32 cols)
    int wm = wave >> 2, wn = wave & 3;
    int l15 = lane & 15, q = lane >> 4;
    int colbase = blockIdx.x * 128 + wn * 32;

    const unsigned short* whp = wh + (size_t)e * N_DIM * D_DIM;

    f32x4 acc[4][2];
    #pragma unroll
    for (int mi = 0; mi < 4; ++mi) {
        acc[mi][0] = (f32x4){0.f, 0.f, 0.f, 0.f};
        acc[mi][1] = (f32x4){0.f, 0.f, 0.f, 0.f};
    }

    // B base for this lane: col = colbase + {0,16} + l15, k offset q*8
    const unsigned short* base0 = whp + (size_t)(colbase + l15) * D_DIM + q * 8;

    // prefetch ALL 4 K-steps' B fragment pairs upfront (8 x 16B loads in flight)
    bf16x8 b0[4], b1[4];
    #pragma unroll
    for (int s = 0; s < 4; ++s) {
        b0[s] = *(const bf16x8*)(base0 + s * 32);
        b1[s] = *(const bf16x8*)(base0 + s * 32 + 16 * D_DIM);
    }

    #pragma unroll
    for (int s = 0; s < 4; ++s) {
        const int kb = (s * 32 + q * 8) * 2;   // byte offset in K
        #pragma unroll
        for (int mi = 0; mi < 4; ++mi) {
            int row  = wm * 64 + mi * 16 + l15;
            int aoff = row * 256 + (kb ^ ((row & 7) << 4));
            bf16x8 a = *(const bf16x8*)((const char*)a_s + aoff);
            acc[mi][0] = __builtin_amdgcn_mfma_f32_16x16x32_bf16(a, b0[s], acc[mi][0], 0, 0, 0);
            acc[mi][1] = __builtin_amdgcn_mfma_f32_16x16x32_bf16(a, b1[s], acc[mi][1], 0, 0, 0);
        }
    }

    // epilogue: C/D layout col=lane&15, row=(lane>>4)*4+reg.
    // Direct fp16 stores into the first N_DIM halfs of the row's fp32 slot.
    const float* bp = bias + (size_t)e * N_DIM;
    float bv0 = bp[colbase + l15];
    float bv1 = bp[colbase + 16 + l15];

    #pragma unroll
    for (int mi = 0; mi < 4; ++mi) {
        #pragma unroll
        for (int reg = 0; reg < 4; ++reg) {
            int m = wm * 64 + mi * 16 + q * 4 + reg;
            if (m < cnt) {
                int r = sorted[seg + m];
                __half* lp = (__half*)(out + (size_t)r * N_DIM);
                lp[colbase + l15]      = __float2half(acc[mi][0][reg] + bv0);
                lp[colbase + 16 + l15] = __float2half(acc[mi][1][reg] + bv1);
            }
        }
    }
}

// Softmax over fp16 logits staged in the first 16KB of each 32KB fp32 row slot.
// Reads all 32 values into registers BEFORE the reduction barriers, then overwrites
// the row with fp32 probabilities.
__global__ __launch_bounds__(256)
void softmax_f16(const float* __restrict__ x,
                 const float* __restrict__ tlo,
                 const float* __restrict__ thi,
                 float* __restrict__ out) {
    int r = blockIdx.x;
    int tid = threadIdx.x;
    float th = x[(size_t)r * D_DIM];
    bool valid = false;
    #pragma unroll
    for (int i = 0; i < E_NUM; ++i) {
        if (th > tlo[i] && th <= thi[i]) valid = true;
    }
    float* row = out + (size_t)r * N_DIM;

    if (!valid) {
        float4 z = make_float4(0.f, 0.f, 0.f, 0.f);
        #pragma unroll
        for (int c = 0; c < 4; ++c) {
            *(float4*)(row + c * 2048 + tid * 8)     = z;
            *(float4*)(row + c * 2048 + tid * 8 + 4) = z;
        }
        return;
    }

    float vv[32];
    float mx = -INFINITY;
    const __half* hp = (const __half*)row;
    #pragma unroll
    for (int c = 0; c < 4; ++c) {
        uint4 u = *(const uint4*)(hp + c * 2048 + tid * 8);
        const __half2* h2 = (const __half2*)&u;
        #pragma unroll
        for (int j = 0; j < 4; ++j) {
            float2 f = __half22float2(h2[j]);
            vv[c * 8 + 2 * j]     = f.x;
            vv[c * 8 + 2 * j + 1] = f.y;
            mx = fmaxf(mx, fmaxf(f.x, f.y));
        }
    }

    __shared__ float red[8];
    #pragma unroll
    for (int o = 1; o < 64; o <<= 1) mx = fmaxf(mx, __shfl_xor(mx, o));
    if ((tid & 63) == 0) red[tid >> 6] = mx;
    __syncthreads();
    mx = fmaxf(fmaxf(red[0], red[1]), fmaxf(red[2], red[3]));

    float sum = 0.f;
    #pragma unroll
    for (int i = 0; i < 32; ++i) {
        vv[i] = expf(vv[i] - mx);
        sum += vv[i];
    }
    #pragma unroll
    for (int o = 1; o < 64; o <<= 1) sum += __shfl_xor(sum, o);
    if ((tid & 63) == 0) red[4 + (tid >> 6)] = sum;
    __syncthreads();
    sum = red[4] + red[5] + red[6] + red[7];

    float inv = 1.0f / sum;
    #pragma unroll
    for (int c = 0; c < 4; ++c) {
        float4 o0, o1;
        o0.x = vv[c * 8 + 0] * inv; o0.y = vv[c * 8 + 1] * inv;
        o0.z = vv[c * 8 + 2] * inv; o0.w = vv[c * 8 + 3] * inv;
        o1.x = vv[c * 8 + 4] * inv; o1.y = vv[c * 8 + 5] * inv;
        o1.z = vv[c * 8 + 6] * inv; o1.w = vv[c * 8 + 7] * inv;
        *(float4*)(row + c * 2048 + tid * 8)     = o0;
        *(float4*)(row + c * 2048 + tid * 8 + 4) = o1;
    }
}

// ---------------- fallback path (workspace too small): bin + fp32 GEMM + softmax ------

__global__ __launch_bounds__(1024)
void bin_kernel(const float* __restrict__ x,
                const float* __restrict__ tlo,
                const float* __restrict__ thi,
                int* __restrict__ ws_i, int m_tile) {
    __shared__ int cnt_s[E_NUM];
    __shared__ int off_s[E_NUM];
    __shared__ int cur_s[E_NUM];
    __shared__ int e_row[B_ROWS];

    int tid = threadIdx.x;
    if (tid < E_NUM) cnt_s[tid] = 0;
    __syncthreads();

    for (int r = tid; r < B_ROWS; r += 1024) {
        float th = x[(size_t)r * D_DIM];
        int e = -1;
        #pragma unroll
        for (int i = 0; i < E_NUM; ++i) {
            if (e < 0 && th > tlo[i] && th <= thi[i]) e = i;
        }
        e_row[r] = e;
        if (e >= 0) atomicAdd(&cnt_s[e], 1);
    }
    __syncthreads();

    if (tid == 0) {
        int off = 0;
        for (int e = 0; e < E_NUM; ++e) {
            ws_i[448 + e] = cnt_s[e];
            off_s[e] = off;
            cur_s[e] = off;
            off += cnt_s[e];
        }
        int nt = 0;
        for (int e = 0; e < E_NUM; ++e) {
            int c = cnt_s[e];
            int s = off_s[e];
            for (int t0 = 0; t0 < c && nt < 72; t0 += m_tile) {
                ws_i[8 + nt]   = e;
                ws_i[96 + nt]  = s + t0;
                ws_i[184 + nt] = (c - t0 < m_tile) ? (c - t0) : m_tile;
                ++nt;
            }
        }
        ws_i[0] = nt;
    }
    __syncthreads();

    for (int r = tid; r < B_ROWS; r += 1024) {
        int e = e_row[r];
        if (e >= 0) {
            int p = atomicAdd(&cur_s[e], 1);
            ws_i[512 + p] = r;
        }
    }
}

__device__ __forceinline__ void fma4(float4& ac, float xs, const float4& wv) {
    ac.x = fmaf(xs, wv.x, ac.x);
    ac.y = fmaf(xs, wv.y, ac.y);
    ac.z = fmaf(xs, wv.z, ac.z);
    ac.w = fmaf(xs, wv.w, ac.w);
}

__global__ __launch_bounds__(256)
void gemm_kernel(const float* __restrict__ x,
                 const float* __restrict__ W,
                 const float* __restrict__ bias,
                 const int* __restrict__ ws_i,
                 float* __restrict__ out) {
    int bt = blockIdx.y;
    if (bt >= ws_i[0]) return;
    int e   = ws_i[8 + bt];
    int seg = ws_i[96 + bt];
    int cnt = ws_i[184 + bt];
    const int* sorted = ws_i + 512;

    __shared__ float x_s[64][D_DIM];
    __shared__ int   rows_s[64];

    int tid = threadIdx.x;
    if (tid < 64) rows_s[tid] = (tid < cnt) ? sorted[seg + tid] : -1;
    __syncthreads();

    #pragma unroll
    for (int c = 0; c < 8; ++c) {
        int idx = c * 256 + tid;
        int i = idx >> 5;
        int k4 = idx & 31;
        int r = rows_s[i];
        float4 v;
        if (r >= 0) v = *(const float4*)(x + (size_t)r * D_DIM + k4 * 4);
        else        v = make_float4(0.f, 0.f, 0.f, 0.f);
        *(float4*)(&x_s[i][k4 * 4]) = v;
    }
    __syncthreads();

    int nidx = tid & 63;
    int mg   = tid >> 6;
    int col  = blockIdx.x * 256 + nidx * 4;
    const float* Wp = W + ((size_t)e * D_DIM) * N_DIM + col;

    float4 acc[16];
    #pragma unroll
    for (int i = 0; i < 16; ++i) acc[i] = make_float4(0.f, 0.f, 0.f, 0.f);

    for (int k = 0; k < D_DIM; k += 4) {
        float4 w0 = *(const float4*)(Wp + (size_t)(k + 0) * N_DIM);
        float4 w1 = *(const float4*)(Wp + (size_t)(k + 1) * N_DIM);
        float4 w2 = *(const float4*)(Wp + (size_t)(k + 2) * N_DIM);
        float4 w3 = *(const float4*)(Wp + (size_t)(k + 3) * N_DIM);
        #pragma unroll
        for (int i = 0; i < 16; ++i) {
            float4 xv = *(const float4*)(&x_s[mg * 16 + i][k]);
            fma4(acc[i], xv.x, w0);
            fma4(acc[i], xv.y, w1);
            fma4(acc[i], xv.z, w2);
            fma4(acc[i], xv.w, w3);
        }
    }

    float4 bv = *(const float4*)(bias + (size_t)e * N_DIM + col);
    #pragma unroll
    for (int i = 0; i < 16; ++i) {
        int m = mg * 16 + i;
        if (m < cnt) {
            int r = rows_s[m];
            float4 o = acc[i];
            o.x += bv.x; o.y += bv.y; o.z += bv.z; o.w += bv.w;
            *(float4*)(out + (size_t)r * N_DIM + col) = o;
        }
    }
}

__global__ __launch_bounds__(256)
void softmax_kernel(const float* __restrict__ x,
                    const float* __restrict__ tlo,
                    const float* __restrict__ thi,
                    float* __restrict__ out) {
    int r = blockIdx.x;
    int tid = threadIdx.x;
    float th = x[(size_t)r * D_DIM];
    bool valid = false;
    #pragma unroll
    for (int i = 0; i < E_NUM; ++i) {
        if (th > tlo[i] && th <= thi[i]) valid = true;
    }
    float* row = out + (size_t)r * N_DIM;

    if (!valid) {
        float4 z = make_float4(0.f, 0.f, 0.f, 0.f);
        #pragma unroll
        for (int c = 0; c < 8; ++c)
            *(float4*)(row + c * 1024 + tid * 4) = z;
        return;
    }

    float4 v[8];
    float mx = -INFINITY;
    #pragma unroll
    for (int c = 0; c < 8; ++c) {
        v[c] = *(const float4*)(row + c * 1024 + tid * 4);
        mx = fmaxf(mx, fmaxf(fmaxf(v[c].x, v[c].y), fmaxf(v[c].z, v[c].w)));
    }

    __shared__ float red[8];
    #pragma unroll
    for (int o = 1; o < 64; o <<= 1) mx = fmaxf(mx, __shfl_xor(mx, o));
    if ((tid & 63) == 0) red[tid >> 6] = mx;
    __syncthreads();
    mx = fmaxf(fmaxf(red[0], red[1]), fmaxf(red[2], red[3]));

    float sum = 0.f;
    #pragma unroll
    for (int c = 0; c < 8; ++c) {
        v[c].x = expf(v[c].x - mx);
        v[c].y = expf(v[c].y - mx);
        v[c].z = expf(v[c].z - mx);
        v[c].w = expf(v[c].w - mx);
        sum += v[c].x + v[c].y + v[c].z + v[c].w;
    }
    #pragma unroll
    for (int o = 1; o < 64; o <<= 1) sum += __shfl_xor(sum, o);
    if ((tid & 63) == 0) red[4 + (tid >> 6)] = sum;
    __syncthreads();
    sum = red[4] + red[5] + red[6] + red[7];

    float inv = 1.0f / sum;
    #pragma unroll
    for (int c = 0; c < 8; ++c) {
        float4 o;
        o.x = v[c].x * inv; o.y = v[c].y * inv;
        o.z = v[c].z * inv; o.w = v[c].w * inv;
        *(float4*)(row + c * 1024 + tid * 4) = o;
    }
}

extern "C" void kernel_launch(void* const* d_in, const int* in_sizes, int n_in,
                              void* d_out, int out_size, void* d_ws, size_t ws_size,
                              hipStream_t stream) {
    const float* x   = (const float*)d_in[0];
    const float* W   = (const float*)d_in[1];
    const float* b   = (const float*)d_in[2];
    const float* tlo = (const float*)d_in[3];
    const float* thi = (const float*)d_in[4];
    float* out = (float*)d_out;
    int* ws_i = (int*)d_ws;

    const size_t meta = 65536;
    const size_t wsz = (size_t)E_NUM * N_DIM * D_DIM;
    unsigned short* wh = (unsigned short*)((char*)d_ws + meta);
    size_t need = meta + wsz * sizeof(unsigned short);
    bool fast = (ws_size >= need);

    if (fast) {
        bin_convert_kernel<<<1025, 1024, 0, stream>>>(x, W, tlo, thi, ws_i, wh);
        // tiles <= 32 full + 8 partials = 40
        gemm_mfma<<<dim3(N_DIM / 128, 40), 512, 0, stream>>>(x, wh, b, ws_i, out);
        softmax_f16<<<B_ROWS, 256, 0, stream>>>(x, tlo, thi, out);
    } else {
        bin_kernel<<<1, 1024, 0, stream>>>(x, tlo, thi, ws_i, 64);
        gemm_kernel<<<dim3(N_DIM / 256, 72), 256, 0, stream>>>(x, W, b, ws_i, out);
        softmax_kernel<<<B_ROWS, 256, 0, stream>>>(x, tlo, thi, out);
    }
}

// Round 16
// 85.872 us; speedup vs baseline: 1.2347x; 1.0992x over previous
//
#include <hip/hip_runtime.h>
#include <hip/hip_fp16.h>
#include <math.h>

// Problem: E=8, B=4096, D=128, N=8192.
// out[b,n] = softmax_n( x[b,:] @ W[e(b)] + bias[e(b)] ) for the (unique) bin e(b), else 0.
//
// Round 16 = R15 (94.4 us) + convert FUSED INTO GEMM:
//   Each gemm block stages its own 128-col B-slice fp32->bf16 from W into LDS
//   (coalesced n-contiguous reads; convert's proven 136-pad + chunk-XOR transpose),
//   loads its 8 B fragments LDS->regs, then REUSES the LDS for the A tile.
//   K-loop + epilogue byte-identical to R15. Kills the wh round-trip (16 MB write +
//   16 MB read) and the convert kernel/launch; W rereads are XCD-local L2 hits
//   (same-col blocks: y-stride 64 % 8 == 0). bin returns to standalone 1024-thr kernel.
// Same f2bf rounding -> absmax must stay exactly 1.220703e-4.
// Lessons kept: no min-waves launch_bounds (R3/R6); no per-lane gathered K-loop
// streams (R4); single-bf16 within threshold (R9); fp16 logit staging (R10);
// one change per round + revert path (R11-R15).

#define B_ROWS 4096
#define D_DIM  128
#define N_DIM  8192
#define E_NUM  8

typedef __attribute__((ext_vector_type(8))) __bf16 bf16x8;
typedef __attribute__((ext_vector_type(4))) float  f32x4;

__device__ __forceinline__ unsigned short f2bf(float f) {
    unsigned int u = __float_as_uint(f);
    unsigned int r = u + 0x7FFFu + ((u >> 16) & 1u);   // round-to-nearest-even
    return (unsigned short)(r >> 16);
}

// ws int layout:
//   [0]         n_tiles
//   [8..79]     tile_e
//   [96..167]   tile_start
//   [184..255]  tile_cnt
//   [448..455]  per-expert counts
//   [512..4607] sorted row indices (grouped by expert)

__global__ __launch_bounds__(1024)
void bin_kernel(const float* __restrict__ x,
                const float* __restrict__ tlo,
                const float* __restrict__ thi,
                int* __restrict__ ws_i, int m_tile) {
    __shared__ int cnt_s[E_NUM];
    __shared__ int off_s[E_NUM];
    __shared__ int cur_s[E_NUM];
    __shared__ int e_row[B_ROWS];

    int tid = threadIdx.x;
    if (tid < E_NUM) cnt_s[tid] = 0;
    __syncthreads();

    for (int r = tid; r < B_ROWS; r += 1024) {
        float th = x[(size_t)r * D_DIM];   // x[r, 0]
        int e = -1;
        #pragma unroll
        for (int i = 0; i < E_NUM; ++i) {
            if (e < 0 && th > tlo[i] && th <= thi[i]) e = i;  // first match
        }
        e_row[r] = e;
        if (e >= 0) atomicAdd(&cnt_s[e], 1);
    }
    __syncthreads();

    if (tid == 0) {
        int off = 0;
        for (int e = 0; e < E_NUM; ++e) {
            ws_i[448 + e] = cnt_s[e];
            off_s[e] = off;
            cur_s[e] = off;
            off += cnt_s[e];
        }
        int nt = 0;
        for (int e = 0; e < E_NUM; ++e) {
            int c = cnt_s[e];
            int s = off_s[e];
            for (int t0 = 0; t0 < c && nt < 72; t0 += m_tile) {
                ws_i[8 + nt]   = e;
                ws_i[96 + nt]  = s + t0;
                ws_i[184 + nt] = (c - t0 < m_tile) ? (c - t0) : m_tile;
                ++nt;
            }
        }
        ws_i[0] = nt;
    }
    __syncthreads();

    for (int r = tid; r < B_ROWS; r += 1024) {
        int e = e_row[r];
        if (e >= 0) {
            int p = atomicAdd(&cur_s[e], 1);
            ws_i[512 + p] = r;
        }
    }
}

// MFMA GEMM + inline W conversion: block = 128 rows x 128 cols, 512 threads = 8 waves
// in 2x4 split; wave = 64 rows x 32 cols, acc[4][2]. Phases:
//  1. stage B: W[e][d][n0..n0+128) fp32 -> bf16, transposed into 34KB LDS
//     (136-pad + chunk-XOR, convert-kernel-proven layout)
//  2. each lane loads its 8 B fragments LDS -> regs (16B-aligned contiguous reads)
//  3. REUSE LDS: stage gathered A rows (fp32->bf16, byte-XOR swizzle)
//  4. K-loop + fp16 epilogue: byte-identical to R15.
__global__ __launch_bounds__(512)
void gemm_conv(const float* __restrict__ x,
               const float* __restrict__ W,
               const float* __restrict__ bias, const int* __restrict__ ws_i,
               float* __restrict__ out) {
    int bt = blockIdx.y;
    if (bt >= ws_i[0]) return;
    int e   = ws_i[8 + bt];
    int seg = ws_i[96 + bt];
    int cnt = ws_i[184 + bt];
    const int* sorted = ws_i + 512;

    __shared__ __align__(16) unsigned short s_buf[128 * 136];  // 34816 B, dual-use B->A

    int tid = threadIdx.x;
    int n0 = blockIdx.x * 128;

    // ---- phase 1: stage B slice fp32 -> bf16 transposed [col][d'] ----
    const float* Wp = W + (size_t)e * D_DIM * N_DIM + n0;
    #pragma unroll
    for (int i = 0; i < 8; ++i) {
        int idx = i * 512 + tid;          // 4096 float4 = 128 d-rows x 32 col-chunks
        int d  = idx >> 5;
        int c4 = idx & 31;
        float4 v = *(const float4*)(Wp + (size_t)d * N_DIM + c4 * 4);
        float fv[4] = {v.x, v.y, v.z, v.w};
        #pragma unroll
        for (int c = 0; c < 4; ++c) {
            int col = c4 * 4 + c;
            int dsw = d ^ (((col >> 2) & 7) << 3);   // chunk-XOR swizzle (convert-proven)
            s_buf[col * 136 + dsw] = f2bf(fv[c]);
        }
    }
    __syncthreads();

    int lane = tid & 63;
    int wave = tid >> 6;            // wm = wave>>2 (64-row half), wn = wave&3 (32 cols)
    int wm = wave >> 2, wn = wave & 3;
    int l15 = lane & 15, q = lane >> 4;
    int colbase0 = wn * 32;
    int colbase  = n0 + colbase0;

    // ---- phase 2: this lane's 8 B fragment loads (LDS -> regs) ----
    // fragment (col, d0..d0+8): stored at col*136 + (d ^ swz(col)); swz is a multiple
    // of 8 and d0 is a multiple of 8, so the 8 elements stay 16B-contiguous.
    bf16x8 b0[4], b1[4];
    #pragma unroll
    for (int s = 0; s < 4; ++s) {
        int d0 = s * 32 + q * 8;
        int c0 = colbase0 + l15;
        int c1 = colbase0 + 16 + l15;
        b0[s] = *(const bf16x8*)(&s_buf[c0 * 136 + (d0 ^ (((c0 >> 2) & 7) << 3))]);
        b1[s] = *(const bf16x8*)(&s_buf[c1 * 136 + (d0 ^ (((c1 >> 2) & 7) << 3))]);
    }
    __syncthreads();   // all B reads done before A overwrites the buffer

    // ---- phase 3: stage gathered A rows (fp32->bf16), byte-XOR swizzle ----
    unsigned short* a_s = s_buf;   // first 32768 B reused
    #pragma unroll
    for (int i = 0; i < 4; ++i) {
        int idx = i * 512 + tid;     // 2048 chunks = 128 rows x 16 x 16B(bf16)
        int row = idx >> 4;
        int ck  = idx & 15;
        unsigned short hq[8] = {0, 0, 0, 0, 0, 0, 0, 0};
        if (row < cnt) {
            int r = sorted[seg + row];
            const float* xp = x + (size_t)r * D_DIM + ck * 8;
            float4 va = *(const float4*)(xp);
            float4 vb = *(const float4*)(xp + 4);
            hq[0] = f2bf(va.x); hq[1] = f2bf(va.y); hq[2] = f2bf(va.z); hq[3] = f2bf(va.w);
            hq[4] = f2bf(vb.x); hq[5] = f2bf(vb.y); hq[6] = f2bf(vb.z); hq[7] = f2bf(vb.w);
        }
        int boff = row * 256 + ((ck * 16) ^ ((row & 7) << 4));
        *(uint4*)((char*)a_s + boff) = *(const uint4*)hq;
    }
    __syncthreads();   // K-loop + epilogue barrier-free from here

    f32x4 acc[4][2];
    #pragma unroll
    for (int mi = 0; mi < 4; ++mi) {
        acc[mi][0] = (f32x4){0.f, 0.f, 0.f, 0.f};
        acc[mi][1] = (f32x4){0.f, 0.f, 0.f, 0.f};
    }

    // ---- phase 4: K-loop (byte-identical to R15) ----
    #pragma unroll
    for (int s = 0; s < 4; ++s) {
        const int kb = (s * 32 + q * 8) * 2;   // byte offset in K
        #pragma unroll
        for (int mi = 0; mi < 4; ++mi) {
            int row  = wm * 64 + mi * 16 + l15;
            int aoff = row * 256 + (kb ^ ((row & 7) << 4));
            bf16x8 a = *(const bf16x8*)((const char*)a_s + aoff);
            acc[mi][0] = __builtin_amdgcn_mfma_f32_16x16x32_bf16(a, b0[s], acc[mi][0], 0, 0, 0);
            acc[mi][1] = __builtin_amdgcn_mfma_f32_16x16x32_bf16(a, b1[s], acc[mi][1], 0, 0, 0);
        }
    }

    // epilogue: C/D layout col=lane&15, row=(lane>>4)*4+reg.
    // Direct fp16 stores into the first N_DIM halfs of the row's fp32 slot.
    const float* bp = bias + (size_t)e * N_DIM;
    float bv0 = bp[colbase + l15];
    float bv1 = bp[colbase + 16 + l15];

    #pragma unroll
    for (int mi = 0; mi < 4; ++mi) {
        #pragma unroll
        for (int reg = 0; reg < 4; ++reg) {
            int m = wm * 64 + mi * 16 + q * 4 + reg;
            if (m < cnt) {
                int r = sorted[seg + m];
                __half* lp = (__half*)(out + (size_t)r * N_DIM);
                lp[colbase + l15]      = __float2half(acc[mi][0][reg] + bv0);
                lp[colbase + 16 + l15] = __float2half(acc[mi][1][reg] + bv1);
            }
        }
    }
}

// Softmax over fp16 logits staged in the first 16KB of each 32KB fp32 row slot.
__global__ __launch_bounds__(256)
void softmax_f16(const float* __restrict__ x,
                 const float* __restrict__ tlo,
                 const float* __restrict__ thi,
                 float* __restrict__ out) {
    int r = blockIdx.x;
    int tid = threadIdx.x;
    float th = x[(size_t)r * D_DIM];
    bool valid = false;
    #pragma unroll
    for (int i = 0; i < E_NUM; ++i) {
        if (th > tlo[i] && th <= thi[i]) valid = true;
    }
    float* row = out + (size_t)r * N_DIM;

    if (!valid) {
        float4 z = make_float4(0.f, 0.f, 0.f, 0.f);
        #pragma unroll
        for (int c = 0; c < 4; ++c) {
            *(float4*)(row + c * 2048 + tid * 8)     = z;
            *(float4*)(row + c * 2048 + tid * 8 + 4) = z;
        }
        return;
    }

    float vv[32];
    float mx = -INFINITY;
    const __half* hp = (const __half*)row;
    #pragma unroll
    for (int c = 0; c < 4; ++c) {
        uint4 u = *(const uint4*)(hp + c * 2048 + tid * 8);
        const __half2* h2 = (const __half2*)&u;
        #pragma unroll
        for (int j = 0; j < 4; ++j) {
            float2 f = __half22float2(h2[j]);
            vv[c * 8 + 2 * j]     = f.x;
            vv[c * 8 + 2 * j + 1] = f.y;
            mx = fmaxf(mx, fmaxf(f.x, f.y));
        }
    }

    __shared__ float red[8];
    #pragma unroll
    for (int o = 1; o < 64; o <<= 1) mx = fmaxf(mx, __shfl_xor(mx, o));
    if ((tid & 63) == 0) red[tid >> 6] = mx;
    __syncthreads();
    mx = fmaxf(fmaxf(red[0], red[1]), fmaxf(red[2], red[3]));

    float sum = 0.f;
    #pragma unroll
    for (int i = 0; i < 32; ++i) {
        vv[i] = expf(vv[i] - mx);
        sum += vv[i];
    }
    #pragma unroll
    for (int o = 1; o < 64; o <<= 1) sum += __shfl_xor(sum, o);
    if ((tid & 63) == 0) red[4 + (tid >> 6)] = sum;
    __syncthreads();
    sum = red[4] + red[5] + red[6] + red[7];

    float inv = 1.0f / sum;
    #pragma unroll
    for (int c = 0; c < 4; ++c) {
        float4 o0, o1;
        o0.x = vv[c * 8 + 0] * inv; o0.y = vv[c * 8 + 1] * inv;
        o0.z = vv[c * 8 + 2] * inv; o0.w = vv[c * 8 + 3] * inv;
        o1.x = vv[c * 8 + 4] * inv; o1.y = vv[c * 8 + 5] * inv;
        o1.z = vv[c * 8 + 6] * inv; o1.w = vv[c * 8 + 7] * inv;
        *(float4*)(row + c * 2048 + tid * 8)     = o0;
        *(float4*)(row + c * 2048 + tid * 8 + 4) = o1;
    }
}

// ---------------- fallback path (workspace too small): bin + fp32 GEMM + softmax ------

__device__ __forceinline__ void fma4(float4& ac, float xs, const float4& wv) {
    ac.x = fmaf(xs, wv.x, ac.x);
    ac.y = fmaf(xs, wv.y, ac.y);
    ac.z = fmaf(xs, wv.z, ac.z);
    ac.w = fmaf(xs, wv.w, ac.w);
}

__global__ __launch_bounds__(256)
void gemm_kernel(const float* __restrict__ x,
                 const float* __restrict__ W,
                 const float* __restrict__ bias,
                 const int* __restrict__ ws_i,
                 float* __restrict__ out) {
    int bt = blockIdx.y;
    if (bt >= ws_i[0]) return;
    int e   = ws_i[8 + bt];
    int seg = ws_i[96 + bt];
    int cnt = ws_i[184 + bt];
    const int* sorted = ws_i + 512;

    __shared__ float x_s[64][D_DIM];
    __shared__ int   rows_s[64];

    int tid = threadIdx.x;
    if (tid < 64) rows_s[tid] = (tid < cnt) ? sorted[seg + tid] : -1;
    __syncthreads();

    #pragma unroll
    for (int c = 0; c < 8; ++c) {
        int idx = c * 256 + tid;
        int i = idx >> 5;
        int k4 = idx & 31;
        int r = rows_s[i];
        float4 v;
        if (r >= 0) v = *(const float4*)(x + (size_t)r * D_DIM + k4 * 4);
        else        v = make_float4(0.f, 0.f, 0.f, 0.f);
        *(float4*)(&x_s[i][k4 * 4]) = v;
    }
    __syncthreads();

    int nidx = tid & 63;
    int mg   = tid >> 6;
    int col  = blockIdx.x * 256 + nidx * 4;
    const float* Wp = W + ((size_t)e * D_DIM) * N_DIM + col;

    float4 acc[16];
    #pragma unroll
    for (int i = 0; i < 16; ++i) acc[i] = make_float4(0.f, 0.f, 0.f, 0.f);

    for (int k = 0; k < D_DIM; k += 4) {
        float4 w0 = *(const float4*)(Wp + (size_t)(k + 0) * N_DIM);
        float4 w1 = *(const float4*)(Wp + (size_t)(k + 1) * N_DIM);
        float4 w2 = *(const float4*)(Wp + (size_t)(k + 2) * N_DIM);
        float4 w3 = *(const float4*)(Wp + (size_t)(k + 3) * N_DIM);
        #pragma unroll
        for (int i = 0; i < 16; ++i) {
            float4 xv = *(const float4*)(&x_s[mg * 16 + i][k]);
            fma4(acc[i], xv.x, w0);
            fma4(acc[i], xv.y, w1);
            fma4(acc[i], xv.z, w2);
            fma4(acc[i], xv.w, w3);
        }
    }

    float4 bv = *(const float4*)(bias + (size_t)e * N_DIM + col);
    #pragma unroll
    for (int i = 0; i < 16; ++i) {
        int m = mg * 16 + i;
        if (m < cnt) {
            int r = rows_s[m];
            float4 o = acc[i];
            o.x += bv.x; o.y += bv.y; o.z += bv.z; o.w += bv.w;
            *(float4*)(out + (size_t)r * N_DIM + col) = o;
        }
    }
}

__global__ __launch_bounds__(256)
void softmax_kernel(const float* __restrict__ x,
                    const float* __restrict__ tlo,
                    const float* __restrict__ thi,
                    float* __restrict__ out) {
    int r = blockIdx.x;
    int tid = threadIdx.x;
    float th = x[(size_t)r * D_DIM];
    bool valid = false;
    #pragma unroll
    for (int i = 0; i < E_NUM; ++i) {
        if (th > tlo[i] && th <= thi[i]) valid = true;
    }
    float* row = out + (size_t)r * N_DIM;

    if (!valid) {
        float4 z = make_float4(0.f, 0.f, 0.f, 0.f);
        #pragma unroll
        for (int c = 0; c < 8; ++c)
            *(float4*)(row + c * 1024 + tid * 4) = z;
        return;
    }

    float4 v[8];
    float mx = -INFINITY;
    #pragma unroll
    for (int c = 0; c < 8; ++c) {
        v[c] = *(const float4*)(row + c * 1024 + tid * 4);
        mx = fmaxf(mx, fmaxf(fmaxf(v[c].x, v[c].y), fmaxf(v[c].z, v[c].w)));
    }

    __shared__ float red[8];
    #pragma unroll
    for (int o = 1; o < 64; o <<= 1) mx = fmaxf(mx, __shfl_xor(mx, o));
    if ((tid & 63) == 0) red[tid >> 6] = mx;
    __syncthreads();
    mx = fmaxf(fmaxf(red[0], red[1]), fmaxf(red[2], red[3]));

    float sum = 0.f;
    #pragma unroll
    for (int c = 0; c < 8; ++c) {
        v[c].x = expf(v[c].x - mx);
        v[c].y = expf(v[c].y - mx);
        v[c].z = expf(v[c].z - mx);
        v[c].w = expf(v[c].w - mx);
        sum += v[c].x + v[c].y + v[c].z + v[c].w;
    }
    #pragma unroll
    for (int o = 1; o < 64; o <<= 1) sum += __shfl_xor(sum, o);
    if ((tid & 63) == 0) red[4 + (tid >> 6)] = sum;
    __syncthreads();
    sum = red[4] + red[5] + red[6] + red[7];

    float inv = 1.0f / sum;
    #pragma unroll
    for (int c = 0; c < 8; ++c) {
        float4 o;
        o.x = v[c].x * inv; o.y = v[c].y * inv;
        o.z = v[c].z * inv; o.w = v[c].w * inv;
        *(float4*)(row + c * 1024 + tid * 4) = o;
    }
}

extern "C" void kernel_launch(void* const* d_in, const int* in_sizes, int n_in,
                              void* d_out, int out_size, void* d_ws, size_t ws_size,
                              hipStream_t stream) {
    const float* x   = (const float*)d_in[0];
    const float* W   = (const float*)d_in[1];
    const float* b   = (const float*)d_in[2];
    const float* tlo = (const float*)d_in[3];
    const float* thi = (const float*)d_in[4];
    float* out = (float*)d_out;
    int* ws_i = (int*)d_ws;

    bool fast = (ws_size >= 65536);   // only metadata needed now

    if (fast) {
        bin_kernel<<<1, 1024, 0, stream>>>(x, tlo, thi, ws_i, 128);
        // tiles <= 32 full + 8 partials = 40
        gemm_conv<<<dim3(N_DIM / 128, 40), 512, 0, stream>>>(x, W, b, ws_i, out);
        softmax_f16<<<B_ROWS, 256, 0, stream>>>(x, tlo, thi, out);
    } else {
        bin_kernel<<<1, 1024, 0, stream>>>(x, tlo, thi, ws_i, 64);
        gemm_kernel<<<dim3(N_DIM / 256, 72), 256, 0, stream>>>(x, W, b, ws_i, out);
        softmax_kernel<<<B_ROWS, 256, 0, stream>>>(x, tlo, thi, out);
    }
}